// Round 11
// baseline (315.982 us; speedup 1.0000x reference)
//
#include <hip/hip_runtime.h>
#include <stdint.h>

#define SEQ 4096
#define DM 1024

typedef __attribute__((ext_vector_type(8))) short short8;    // 8 bf16 = 4 VGPRs
typedef __attribute__((ext_vector_type(4))) float f32x4;
typedef __attribute__((ext_vector_type(16))) float f32x16;
typedef unsigned short ushort_t;

__device__ inline ushort_t f2bf(float f) {
  union { float f; uint32_t u; } v; v.f = f;
  return (ushort_t)((v.u + 0x7FFFu + ((v.u >> 16) & 1u)) >> 16);  // RNE
}
__device__ inline float bf2f(ushort_t h) {
  union { uint32_t u; float f; } v; v.u = ((uint32_t)h) << 16;
  return v.f;
}

// async global->LDS, 16B/lane; LDS dest = wave-uniform base + lane*16
__device__ inline void async_copy16(const void* g, void* lds) {
  __builtin_amdgcn_global_load_lds(
      (const __attribute__((address_space(1))) uint32_t*)g,
      (__attribute__((address_space(3))) uint32_t*)lds, 16, 0, 0);
}

// LDS bank-conflict swizzles (R4 verified: SQ_LDS_BANK_CONFLICT -> 0).
// 32-wide tiles: 4 slots/row, rotate by (row>>1)&3. 64-wide tiles: 8 slots/row,
// rotate by row&7. R11: 32x32 operand reads keep rotation (l32>>1)&3 — per
// 16-lane phase the bank pattern is identical to the verified 16x16 one.

// Fused QKV projection, one dispatch (768 blocks = 3/CU). n0<2048: Q/K,
// 3-phase split-bf16 via 32x32x16 MFMA (2x2 tiles/wave, 24 MFMA + 12 ds_read
// per BK=32 chunk vs 48+16 for 16x16), hi/lo pair out. n0>=2048: V, 1-phase
// hi-only, BK=64, 16x16; epilogue writes V^T directly.
__global__ __launch_bounds__(256, 3)
void gemm_qkv(const ushort_t* __restrict__ A, const ushort_t* __restrict__ Bt,
              ushort_t* __restrict__ Qb, ushort_t* __restrict__ Kb,
              ushort_t* __restrict__ VT) {
  __shared__ ushort_t As[2][128 * 32];
  __shared__ ushort_t Bs[2][128 * 32];
  const int t = threadIdx.x;
  const int wave = t >> 6, lane = t & 63;
  const int quad = lane >> 4, l16 = lane & 15;
  const int l32 = lane & 31, khalf = lane >> 5;
  const int m0 = blockIdx.y * 128, n0 = blockIdx.x * 128;
  const int wm = (wave & 1) * 64, wn = (wave >> 1) * 64;

  if (n0 >= 2048) {
    // ---- V path: 1-phase, BK=64, 16x16, LDS viewed as 128x64 ----
    f32x4 acc[4][4] = {};
    ushort_t* Af = &As[0][0];
    ushort_t* Bf = &Bs[0][0];
    const int srow8 = lane >> 3;
    const int gcol8 = (((lane & 7) - srow8) & 7) * 8;
    const int rs = l16 & 7;
    for (int k0 = 0; k0 < 1024; k0 += 64) {
#pragma unroll
      for (int i = 0; i < 4; ++i) {
        int c = wave * 4 + i;  // 8-row chunk id, 0..15
        async_copy16(A + (size_t)(m0 + c * 8 + srow8) * 2048 + k0 + gcol8,
                     Af + c * 512);
        async_copy16(Bt + (size_t)(n0 + c * 8 + srow8) * 2048 + k0 + gcol8,
                     Bf + c * 512);
      }
      __syncthreads();
#pragma unroll
      for (int q = 0; q < 2; ++q) {
        short8 a[4], b[4];
#pragma unroll
        for (int i = 0; i < 4; ++i) {
          int slot = ((q * 4 + quad + rs) & 7) * 8;
          a[i] = *(const short8*)(Af + (wm + i * 16 + l16) * 64 + slot);
          b[i] = *(const short8*)(Bf + (wn + i * 16 + l16) * 64 + slot);
        }
#pragma unroll
        for (int i = 0; i < 4; ++i)
#pragma unroll
          for (int j = 0; j < 4; ++j)
            acc[i][j] = __builtin_amdgcn_mfma_f32_16x16x32_bf16(a[i], b[j], acc[i][j], 0, 0, 0);
      }
      __syncthreads();
    }
    // direct V^T write: VT[col][row], rows quad*4+r contiguous -> ushort4
    const int cb = n0 - 2048;
#pragma unroll
    for (int i = 0; i < 4; ++i)
#pragma unroll
      for (int j = 0; j < 4; ++j) {
        int row_base = m0 + wm + i * 16 + quad * 4;
        int col = cb + wn + j * 16 + l16;
        ushort4 o;
        o.x = f2bf(acc[i][j][0]); o.y = f2bf(acc[i][j][1]);
        o.z = f2bf(acc[i][j][2]); o.w = f2bf(acc[i][j][3]);
        *(ushort4*)(VT + (size_t)col * SEQ + row_base) = o;
      }
    return;
  }

  // ---- Q/K path: 3-phase, BK=32, 32x32x16 MFMA ----
  const int srow = lane >> 2;
  const int sf = (srow >> 1) & 3;
  const int gcol = (((lane & 3) - sf) & 3) * 8;
  const int rf = (l32 >> 1) & 3;

  f32x16 acc[2][2] = {};

  for (int k0 = 0; k0 < 1024; k0 += 32) {
#pragma unroll
    for (int i = 0; i < 2; ++i) {
      int c = wave * 2 + i;
      const ushort_t* ga = A + (size_t)(m0 + c * 16 + srow) * 2048 + k0 + gcol;
      const ushort_t* gb = Bt + (size_t)(n0 + c * 16 + srow) * 2048 + k0 + gcol;
      async_copy16(ga,        As[0] + c * 512);
      async_copy16(ga + 1024, As[1] + c * 512);
      async_copy16(gb,        Bs[0] + c * 512);
      async_copy16(gb + 1024, Bs[1] + c * 512);
    }
    __syncthreads();
#pragma unroll
    for (int q = 0; q < 2; ++q) {
      const int slot = ((q * 2 + khalf + rf) & 3) * 8;
      short8 a[2], b[2], x[2];
#pragma unroll
      for (int i = 0; i < 2; ++i) {
        a[i] = *(const short8*)(As[0] + (wm + i * 32 + l32) * 32 + slot);
        b[i] = *(const short8*)(Bs[0] + (wn + i * 32 + l32) * 32 + slot);
      }
#pragma unroll
      for (int i = 0; i < 2; ++i)
#pragma unroll
        for (int j = 0; j < 2; ++j)
          acc[i][j] = __builtin_amdgcn_mfma_f32_32x32x16_bf16(a[i], b[j], acc[i][j], 0, 0, 0);
#pragma unroll
      for (int j = 0; j < 2; ++j)
        x[j] = *(const short8*)(Bs[1] + (wn + j * 32 + l32) * 32 + slot);
#pragma unroll
      for (int i = 0; i < 2; ++i)
#pragma unroll
        for (int j = 0; j < 2; ++j)
          acc[i][j] = __builtin_amdgcn_mfma_f32_32x32x16_bf16(a[i], x[j], acc[i][j], 0, 0, 0);
#pragma unroll
      for (int i = 0; i < 2; ++i)
        x[i] = *(const short8*)(As[1] + (wm + i * 32 + l32) * 32 + slot);
#pragma unroll
      for (int i = 0; i < 2; ++i)
#pragma unroll
        for (int j = 0; j < 2; ++j)
          acc[i][j] = __builtin_amdgcn_mfma_f32_32x32x16_bf16(x[i], b[j], acc[i][j], 0, 0, 0);
    }
    __syncthreads();
  }

  ushort_t* Cm = (n0 < 1024) ? Qb : Kb;
  const int cb = n0 & 1023;
#pragma unroll
  for (int i = 0; i < 2; ++i)
#pragma unroll
    for (int j = 0; j < 2; ++j)
#pragma unroll
      for (int r = 0; r < 16; ++r) {
        int row = m0 + wm + i * 32 + (r & 3) + 8 * (r >> 2) + 4 * khalf;
        int col = cb + wn + j * 32 + l32;
        float v = acc[i][j][r];
        ushort_t h = f2bf(v);
        size_t base = (size_t)row * 2048 + col;
        Cm[base] = h;
        Cm[base + 1024] = f2bf(v - bf2f(h));
      }
}

// Scores = Q K^T * scale, fp32 out, 3-phase split-bf16, 32x32x16 MFMA
// (R11: 24 MFMA + 12 ds_read per chunk vs 48+16; 32x32 pipe is ~15% faster
// per FLOP — m06/m119).
__global__ __launch_bounds__(256, 4)
void gemm_sc(const ushort_t* __restrict__ A, const ushort_t* __restrict__ Bt,
             float* __restrict__ C, float scale) {
  const int m0 = blockIdx.y * 128, n0 = blockIdx.x * 128;

  __shared__ ushort_t As[2][128 * 32];
  __shared__ ushort_t Bs[2][128 * 32];
  const int t = threadIdx.x;
  const int wave = t >> 6, lane = t & 63;
  const int l32 = lane & 31, khalf = lane >> 5;
  const int wm = (wave & 1) * 64, wn = (wave >> 1) * 64;
  const int srow = lane >> 2;
  const int sf = (srow >> 1) & 3;
  const int gcol = (((lane & 3) - sf) & 3) * 8;
  const int rf = (l32 >> 1) & 3;

  f32x16 acc[2][2] = {};

  for (int k0 = 0; k0 < 1024; k0 += 32) {
#pragma unroll
    for (int i = 0; i < 2; ++i) {
      int c = wave * 2 + i;
      const ushort_t* ga = A + (size_t)(m0 + c * 16 + srow) * 2048 + k0 + gcol;
      const ushort_t* gb = Bt + (size_t)(n0 + c * 16 + srow) * 2048 + k0 + gcol;
      async_copy16(ga,        As[0] + c * 512);
      async_copy16(ga + 1024, As[1] + c * 512);
      async_copy16(gb,        Bs[0] + c * 512);
      async_copy16(gb + 1024, Bs[1] + c * 512);
    }
    __syncthreads();
#pragma unroll
    for (int q = 0; q < 2; ++q) {
      const int slot = ((q * 2 + khalf + rf) & 3) * 8;
      short8 a[2], b[2], x[2];
#pragma unroll
      for (int i = 0; i < 2; ++i) {
        a[i] = *(const short8*)(As[0] + (wm + i * 32 + l32) * 32 + slot);
        b[i] = *(const short8*)(Bs[0] + (wn + i * 32 + l32) * 32 + slot);
      }
#pragma unroll
      for (int i = 0; i < 2; ++i)
#pragma unroll
        for (int j = 0; j < 2; ++j)
          acc[i][j] = __builtin_amdgcn_mfma_f32_32x32x16_bf16(a[i], b[j], acc[i][j], 0, 0, 0);
#pragma unroll
      for (int j = 0; j < 2; ++j)
        x[j] = *(const short8*)(Bs[1] + (wn + j * 32 + l32) * 32 + slot);
#pragma unroll
      for (int i = 0; i < 2; ++i)
#pragma unroll
        for (int j = 0; j < 2; ++j)
          acc[i][j] = __builtin_amdgcn_mfma_f32_32x32x16_bf16(a[i], x[j], acc[i][j], 0, 0, 0);
#pragma unroll
      for (int i = 0; i < 2; ++i)
        x[i] = *(const short8*)(As[1] + (wm + i * 32 + l32) * 32 + slot);
#pragma unroll
      for (int i = 0; i < 2; ++i)
#pragma unroll
        for (int j = 0; j < 2; ++j)
          acc[i][j] = __builtin_amdgcn_mfma_f32_32x32x16_bf16(x[i], b[j], acc[i][j], 0, 0, 0);
    }
    __syncthreads();
  }

#pragma unroll
  for (int i = 0; i < 2; ++i)
#pragma unroll
    for (int j = 0; j < 2; ++j)
#pragma unroll
      for (int r = 0; r < 16; ++r) {
        int row = m0 + wm + i * 32 + (r & 3) + 8 * (r >> 2) + 4 * khalf;
        int col = n0 + wn + j * 32 + l32;
        C[(size_t)row * SEQ + col] = acc[i][j][r] * scale;
      }
}

// PV: Obuf[z] = P[dense, lda=4096] * VT^T over k-range z. 2048 blocks
// (32m x 16n x 4z, XCD-swizzled flat grid), 128m x 64n tile, 24 KB LDS
// -> ~6 blocks/CU. Per wave: 2 tiles of 32x32, BK=64, plain stores into
// per-z partials (reduce4 sums them).
__global__ __launch_bounds__(256)
void gemm_pv(const ushort_t* __restrict__ P, const ushort_t* __restrict__ Vt,
             float* __restrict__ Obuf) {
  const int id = blockIdx.x;
  const int g = ((id >> 7) << 3) | (id & 7);   // (m,z) group, 0..127
  const int jn = (id >> 3) & 15;               // n tile (64-wide)
  const int z = g & 3, m = g >> 2;
  const int m0 = m * 128, n0 = jn * 64, kbeg = z * 1024;
  float* Ob = Obuf + (size_t)z * SEQ * DM;

  __shared__ ushort_t As[128 * 64];   // 16 KB
  __shared__ ushort_t Bs[64 * 64];    //  8 KB
  const int t = threadIdx.x;
  const int wave = t >> 6, lane = t & 63;
  const int l32 = lane & 31, khalf = lane >> 5;
  const int wm = (wave & 1) * 64, wn = (wave >> 1) * 32;
  const int srow = lane >> 3;
  const int gcol = (((lane & 7) - srow) & 7) * 8;
  const int rrot = lane & 7;   // (operand row)&7 == l32&7 == lane&7

  f32x16 acc[2] = {};
  for (int k0 = kbeg; k0 < kbeg + 1024; k0 += 64) {
#pragma unroll
    for (int i = 0; i < 4; ++i) {
      int c = wave * 4 + i;  // 8-row chunk, 0..15 (A: 128 rows)
      async_copy16(P + (size_t)(m0 + c * 8 + srow) * 4096 + k0 + gcol,
                   As + c * 512);
    }
#pragma unroll
    for (int i = 0; i < 2; ++i) {
      int c = wave * 2 + i;  // 8-row chunk, 0..7 (B: 64 rows)
      async_copy16(Vt + (size_t)(n0 + c * 8 + srow) * SEQ + k0 + gcol,
                   Bs + c * 512);
    }
    __syncthreads();
#pragma unroll
    for (int q = 0; q < 4; ++q) {            // k-step of 16 within the chunk
      const int slot = ((q * 2 + khalf + rrot) & 7) * 8;
      short8 b = *(const short8*)(Bs + (wn + l32) * 64 + slot);
#pragma unroll
      for (int i = 0; i < 2; ++i) {
        short8 a = *(const short8*)(As + (wm + i * 32 + l32) * 64 + slot);
        acc[i] = __builtin_amdgcn_mfma_f32_32x32x16_bf16(a, b, acc[i], 0, 0, 0);
      }
    }
    __syncthreads();
  }
#pragma unroll
  for (int i = 0; i < 2; ++i)
#pragma unroll
    for (int r = 0; r < 16; ++r) {
      int row = m0 + wm + i * 32 + (r & 3) + 8 * (r >> 2) + 4 * khalf;
      int col = n0 + wn + l32;
      Ob[(size_t)row * DM + col] = acc[i][r];
    }
}

// out = Obuf[0] + Obuf[1] + Obuf[2] + Obuf[3], float4-vectorized.
__global__ __launch_bounds__(256)
void reduce4(const float* __restrict__ B, float* __restrict__ out) {
  const size_t i = ((size_t)blockIdx.x * 256 + threadIdx.x) * 4;
  const size_t n = (size_t)SEQ * DM;
  float4 s0 = *(const float4*)(B + i);
  float4 s1 = *(const float4*)(B + n + i);
  float4 s2 = *(const float4*)(B + 2 * n + i);
  float4 s3 = *(const float4*)(B + 3 * n + i);
  float4 o;
  o.x = s0.x + s1.x + s2.x + s3.x;
  o.y = s0.y + s1.y + s2.y + s3.y;
  o.z = s0.z + s1.z + s2.z + s3.z;
  o.w = s0.w + s1.w + s2.w + s3.w;
  *(float4*)(out + i) = o;
}

// Merged prep: z<3 -> W transpose+split into Wall; z==3 -> x split into Xp.
// Grid (16, 64, 4); W-paths no-op for by>=16.
__global__ __launch_bounds__(256)
void prep(const float* __restrict__ x, const float* __restrict__ W0,
          const float* __restrict__ W1, const float* __restrict__ W2,
          ushort_t* __restrict__ Xp, ushort_t* __restrict__ Wall) {
  const int zz = blockIdx.z;
  const int tx = threadIdx.x & 63, ty = threadIdx.x >> 6;
  if (zz == 3) {
    const int bc = blockIdx.x * 64, br = blockIdx.y * 64;
#pragma unroll
    for (int i = ty; i < 64; i += 4) {
      float v = x[(size_t)(br + i) * 1024 + bc + tx];
      ushort_t h = f2bf(v);
      Xp[(size_t)(br + i) * 2048 + bc + tx] = h;
      Xp[(size_t)(br + i) * 2048 + 1024 + bc + tx] = f2bf(v - bf2f(h));
    }
    return;
  }
  if (blockIdx.y >= 16) return;
  const float* W = (zz == 0) ? W0 : (zz == 1) ? W1 : W2;
  ushort_t* Wo = Wall + (size_t)zz * DM * 2048;
  __shared__ float tile[64][65];
  const int bn = blockIdx.x * 64, bk = blockIdx.y * 64;
#pragma unroll
  for (int i = ty; i < 64; i += 4)
    tile[i][tx] = W[(size_t)(bk + i) * DM + bn + tx];
  __syncthreads();
#pragma unroll
  for (int i = ty; i < 64; i += 4) {
    float v = tile[tx][i];
    ushort_t h = f2bf(v);
    Wo[(size_t)(bn + i) * 2048 + bk + tx] = h;
    Wo[(size_t)(bn + i) * 2048 + 1024 + bk + tx] = f2bf(v - bf2f(h));
  }
}

// one block per row; reads fp32 scores row (stride SEQ), writes dense bf16 P row
__global__ __launch_bounds__(256)
void softmax_rows(const float* __restrict__ S, ushort_t* __restrict__ Pd) {
  const int row = blockIdx.x;
  const int t = threadIdx.x, lane = t & 63, wave = t >> 6;
  const float4* s4 = (const float4*)(S + (size_t)row * SEQ);
  float4 v[4];
  float m = -3.4e38f;
#pragma unroll
  for (int i = 0; i < 4; ++i) {
    v[i] = s4[i * 256 + t];
    m = fmaxf(m, fmaxf(fmaxf(v[i].x, v[i].y), fmaxf(v[i].z, v[i].w)));
  }
  __shared__ float redm[4], reds[4];
#pragma unroll
  for (int o = 32; o; o >>= 1) m = fmaxf(m, __shfl_xor(m, o));
  if (lane == 0) redm[wave] = m;
  __syncthreads();
  m = fmaxf(fmaxf(redm[0], redm[1]), fmaxf(redm[2], redm[3]));
  float sum = 0.f;
#pragma unroll
  for (int i = 0; i < 4; ++i) {
    v[i].x = __expf(v[i].x - m); v[i].y = __expf(v[i].y - m);
    v[i].z = __expf(v[i].z - m); v[i].w = __expf(v[i].w - m);
    sum += v[i].x + v[i].y + v[i].z + v[i].w;
  }
#pragma unroll
  for (int o = 32; o; o >>= 1) sum += __shfl_xor(sum, o);
  if (lane == 0) reds[wave] = sum;
  __syncthreads();
  const float inv = 1.f / (reds[0] + reds[1] + reds[2] + reds[3]);
  ushort4* p4 = (ushort4*)(Pd + (size_t)row * SEQ);
#pragma unroll
  for (int i = 0; i < 4; ++i) {
    ushort4 o;
    o.x = f2bf(v[i].x * inv); o.y = f2bf(v[i].y * inv);
    o.z = f2bf(v[i].z * inv); o.w = f2bf(v[i].w * inv);
    p4[i * 256 + t] = o;
  }
}

extern "C" void kernel_launch(void* const* d_in, const int* in_sizes, int n_in,
                              void* d_out, int out_size, void* d_ws, size_t ws_size,
                              hipStream_t stream) {
  const float* x  = (const float*)d_in[0];
  const float* Wq = (const float*)d_in[1];
  const float* Wk = (const float*)d_in[2];
  const float* Wv = (const float*)d_in[3];
  float* out = (float*)d_out;
  char* ws = (char*)d_ws;
  const size_t MB = (size_t)1 << 20;
  // ws layout (140 MB). Pd aliases Xp/Wall/Qb-head (all dead at softmax);
  // Obuf aliases S (dead after softmax).
  ushort_t* Xp   = (ushort_t*)(ws + 0 * MB);    // 16 MB [SEQ x 2048] hi|lo
  ushort_t* Wall = (ushort_t*)(ws + 16 * MB);   // 12 MB [3072 x 2048]
  ushort_t* Qb   = (ushort_t*)(ws + 28 * MB);   // 16 MB [SEQ x 2048]
  ushort_t* Kb   = (ushort_t*)(ws + 44 * MB);   // 16 MB
  ushort_t* VT   = (ushort_t*)(ws + 68 * MB);   //  8 MB [DM x SEQ]
  float*    S    = (float*)(ws + 76 * MB);      // 64 MB [SEQ x SEQ]
  ushort_t* Pd   = (ushort_t*)(ws + 0 * MB);    // 32 MB [SEQ x SEQ] dense bf16
  float*    Obuf = (float*)(ws + 76 * MB);      // 64 MB = 4 x [SEQ x DM] fp32

  // 1) split inputs into bf16 hi/lo pairs (x elementwise, W transposed)
  prep<<<dim3(16, 64, 4), 256, 0, stream>>>(x, Wq, Wk, Wv, Xp, Wall);

  // 2) fused QKV projection (768 blocks = 3/CU); V path writes VT directly
  gemm_qkv<<<dim3(3 * DM / 128, SEQ / 128), 256, 0, stream>>>(
      Xp, Wall, Qb, Kb, VT);

  // 3) scores = Q K^T / 32, fp32
  gemm_sc<<<dim3(SEQ / 128, SEQ / 128), 256, 0, stream>>>(Qb, Kb, S, 0.03125f);

  // 4) row softmax -> dense bf16 P (over dead Xp/Wall region)
  softmax_rows<<<SEQ, 256, 0, stream>>>(S, Pd);

  // 5) partial PV into 4 split-K buffers (2048 blocks, 128x64 tiles)
  gemm_pv<<<2048, 256, 0, stream>>>(Pd, VT, Obuf);

  // 6) out = sum of the 4 partials
  reduce4<<<SEQ * DM / 1024, 256, 0, stream>>>(Obuf, out);
}

// Round 12
// 293.694 us; speedup vs baseline: 1.0759x; 1.0759x over previous
//
#include <hip/hip_runtime.h>
#include <stdint.h>

#define SEQ 4096
#define DM 1024

typedef __attribute__((ext_vector_type(8))) short short8;    // 8 bf16 = 4 VGPRs
typedef __attribute__((ext_vector_type(4))) float f32x4;
typedef __attribute__((ext_vector_type(16))) float f32x16;
typedef unsigned short ushort_t;

__device__ inline ushort_t f2bf(float f) {
  union { float f; uint32_t u; } v; v.f = f;
  return (ushort_t)((v.u + 0x7FFFu + ((v.u >> 16) & 1u)) >> 16);  // RNE
}
__device__ inline float bf2f(ushort_t h) {
  union { uint32_t u; float f; } v; v.u = ((uint32_t)h) << 16;
  return v.f;
}

// async global->LDS, 16B/lane; LDS dest = wave-uniform base + lane*16
__device__ inline void async_copy16(const void* g, void* lds) {
  __builtin_amdgcn_global_load_lds(
      (const __attribute__((address_space(1))) uint32_t*)g,
      (__attribute__((address_space(3))) uint32_t*)lds, 16, 0, 0);
}

// LDS swizzles — MEASURED rules, not modeled (R4/R11):
//  * 32-wide tiles + 16x16 operand reads (rot (row>>1)&3): 0 conflicts.
//  * 32-wide tiles + 32x32 operand reads (same rot): 8.4M conflicts — DO NOT.
//  * 64-wide tiles + 32x32 reads (rot row&7): 0 conflicts in practice.

// Fused QKV projection (R10-exact), one dispatch (768 blocks = 3/CU).
// n0<2048: Q/K, 3-phase split-bf16 16x16x32, hi/lo pair out, BK=32.
// n0>=2048: V, 1-phase hi-only, BK=64; epilogue writes V^T directly.
__global__ __launch_bounds__(256, 3)
void gemm_qkv(const ushort_t* __restrict__ A, const ushort_t* __restrict__ Bt,
              ushort_t* __restrict__ Qb, ushort_t* __restrict__ Kb,
              ushort_t* __restrict__ VT) {
  __shared__ ushort_t As[2][128 * 32];
  __shared__ ushort_t Bs[2][128 * 32];
  const int t = threadIdx.x;
  const int wave = t >> 6, lane = t & 63;
  const int quad = lane >> 4, l16 = lane & 15;
  const int m0 = blockIdx.y * 128, n0 = blockIdx.x * 128;
  const int wm = (wave & 1) * 64, wn = (wave >> 1) * 64;

  f32x4 acc[4][4] = {};

  if (n0 >= 2048) {
    // ---- V path: 1-phase, BK=64, 16x16, LDS viewed as 128x64 ----
    ushort_t* Af = &As[0][0];
    ushort_t* Bf = &Bs[0][0];
    const int srow8 = lane >> 3;
    const int gcol8 = (((lane & 7) - srow8) & 7) * 8;
    const int rs = l16 & 7;
    for (int k0 = 0; k0 < 1024; k0 += 64) {
#pragma unroll
      for (int i = 0; i < 4; ++i) {
        int c = wave * 4 + i;  // 8-row chunk id, 0..15
        async_copy16(A + (size_t)(m0 + c * 8 + srow8) * 2048 + k0 + gcol8,
                     Af + c * 512);
        async_copy16(Bt + (size_t)(n0 + c * 8 + srow8) * 2048 + k0 + gcol8,
                     Bf + c * 512);
      }
      __syncthreads();
#pragma unroll
      for (int q = 0; q < 2; ++q) {
        short8 a[4], b[4];
#pragma unroll
        for (int i = 0; i < 4; ++i) {
          int slot = ((q * 4 + quad + rs) & 7) * 8;
          a[i] = *(const short8*)(Af + (wm + i * 16 + l16) * 64 + slot);
          b[i] = *(const short8*)(Bf + (wn + i * 16 + l16) * 64 + slot);
        }
#pragma unroll
        for (int i = 0; i < 4; ++i)
#pragma unroll
          for (int j = 0; j < 4; ++j)
            acc[i][j] = __builtin_amdgcn_mfma_f32_16x16x32_bf16(a[i], b[j], acc[i][j], 0, 0, 0);
      }
      __syncthreads();
    }
    // direct V^T write: VT[col][row], rows quad*4+r contiguous -> ushort4
    const int cb = n0 - 2048;
#pragma unroll
    for (int i = 0; i < 4; ++i)
#pragma unroll
      for (int j = 0; j < 4; ++j) {
        int row_base = m0 + wm + i * 16 + quad * 4;
        int col = cb + wn + j * 16 + l16;
        ushort4 o;
        o.x = f2bf(acc[i][j][0]); o.y = f2bf(acc[i][j][1]);
        o.z = f2bf(acc[i][j][2]); o.w = f2bf(acc[i][j][3]);
        *(ushort4*)(VT + (size_t)col * SEQ + row_base) = o;
      }
    return;
  }

  // ---- Q/K path: 3-phase, BK=32, 16x16x32 ----
  const int srow = lane >> 2;
  const int sf = (srow >> 1) & 3;
  const int gcol = (((lane & 3) - sf) & 3) * 8;
  const int rf = (l16 >> 1) & 3;
  const int aslot = ((quad + rf) & 3) * 8;

  for (int k0 = 0; k0 < 1024; k0 += 32) {
#pragma unroll
    for (int i = 0; i < 2; ++i) {
      int c = wave * 2 + i;
      const ushort_t* ga = A + (size_t)(m0 + c * 16 + srow) * 2048 + k0 + gcol;
      const ushort_t* gb = Bt + (size_t)(n0 + c * 16 + srow) * 2048 + k0 + gcol;
      async_copy16(ga,        As[0] + c * 512);
      async_copy16(ga + 1024, As[1] + c * 512);
      async_copy16(gb,        Bs[0] + c * 512);
      async_copy16(gb + 1024, Bs[1] + c * 512);
    }
    __syncthreads();
    short8 a[4], b[4], x[4];
#pragma unroll
    for (int i = 0; i < 4; ++i) {
      a[i] = *(const short8*)(As[0] + (wm + i * 16 + l16) * 32 + aslot);
      b[i] = *(const short8*)(Bs[0] + (wn + i * 16 + l16) * 32 + aslot);
    }
#pragma unroll
    for (int i = 0; i < 4; ++i)
#pragma unroll
      for (int j = 0; j < 4; ++j)
        acc[i][j] = __builtin_amdgcn_mfma_f32_16x16x32_bf16(a[i], b[j], acc[i][j], 0, 0, 0);
#pragma unroll
    for (int j = 0; j < 4; ++j)
      x[j] = *(const short8*)(Bs[1] + (wn + j * 16 + l16) * 32 + aslot);
#pragma unroll
    for (int i = 0; i < 4; ++i)
#pragma unroll
      for (int j = 0; j < 4; ++j)
        acc[i][j] = __builtin_amdgcn_mfma_f32_16x16x32_bf16(a[i], x[j], acc[i][j], 0, 0, 0);
#pragma unroll
    for (int i = 0; i < 4; ++i)
      x[i] = *(const short8*)(As[1] + (wm + i * 16 + l16) * 32 + aslot);
#pragma unroll
    for (int i = 0; i < 4; ++i)
#pragma unroll
      for (int j = 0; j < 4; ++j)
        acc[i][j] = __builtin_amdgcn_mfma_f32_16x16x32_bf16(x[i], b[j], acc[i][j], 0, 0, 0);
    __syncthreads();
  }

  ushort_t* Cm = (n0 < 1024) ? Qb : Kb;
  const int cb = n0 & 1023;
#pragma unroll
  for (int i = 0; i < 4; ++i)
#pragma unroll
    for (int j = 0; j < 4; ++j)
#pragma unroll
      for (int r = 0; r < 4; ++r) {
        int row = m0 + wm + i * 16 + quad * 4 + r;
        int col = cb + wn + j * 16 + l16;
        float v = acc[i][j][r];
        ushort_t h = f2bf(v);
        size_t base = (size_t)row * 2048 + col;
        Cm[base] = h;
        Cm[base + 1024] = f2bf(v - bf2f(h));
      }
}

// Scores = Q K^T * scale (R10-exact), fp32 out, 3-phase split-bf16 16x16x32,
// 48 MFMA/barrier. ~100us / 1010 TF — structural ceiling of this K-loop family.
__global__ __launch_bounds__(256, 4)
void gemm_sc(const ushort_t* __restrict__ A, const ushort_t* __restrict__ Bt,
             float* __restrict__ C, float scale) {
  const int m0 = blockIdx.y * 128, n0 = blockIdx.x * 128;

  __shared__ ushort_t As[2][128 * 32];
  __shared__ ushort_t Bs[2][128 * 32];
  const int t = threadIdx.x;
  const int wave = t >> 6, lane = t & 63;
  const int quad = lane >> 4, l16 = lane & 15;
  const int wm = (wave & 1) * 64, wn = (wave >> 1) * 64;
  const int srow = lane >> 2;
  const int sf = (srow >> 1) & 3;
  const int gcol = (((lane & 3) - sf) & 3) * 8;
  const int rf = (l16 >> 1) & 3;
  const int aslot = ((quad + rf) & 3) * 8;

  f32x4 acc[4][4] = {};

  for (int k0 = 0; k0 < 1024; k0 += 32) {
#pragma unroll
    for (int i = 0; i < 2; ++i) {
      int c = wave * 2 + i;
      const ushort_t* ga = A + (size_t)(m0 + c * 16 + srow) * 2048 + k0 + gcol;
      const ushort_t* gb = Bt + (size_t)(n0 + c * 16 + srow) * 2048 + k0 + gcol;
      async_copy16(ga,        As[0] + c * 512);
      async_copy16(ga + 1024, As[1] + c * 512);
      async_copy16(gb,        Bs[0] + c * 512);
      async_copy16(gb + 1024, Bs[1] + c * 512);
    }
    __syncthreads();
    short8 a[4], b[4], x[4];
#pragma unroll
    for (int i = 0; i < 4; ++i) {
      a[i] = *(const short8*)(As[0] + (wm + i * 16 + l16) * 32 + aslot);
      b[i] = *(const short8*)(Bs[0] + (wn + i * 16 + l16) * 32 + aslot);
    }
#pragma unroll
    for (int i = 0; i < 4; ++i)
#pragma unroll
      for (int j = 0; j < 4; ++j)
        acc[i][j] = __builtin_amdgcn_mfma_f32_16x16x32_bf16(a[i], b[j], acc[i][j], 0, 0, 0);
#pragma unroll
    for (int j = 0; j < 4; ++j)
      x[j] = *(const short8*)(Bs[1] + (wn + j * 16 + l16) * 32 + aslot);
#pragma unroll
    for (int i = 0; i < 4; ++i)
#pragma unroll
      for (int j = 0; j < 4; ++j)
        acc[i][j] = __builtin_amdgcn_mfma_f32_16x16x32_bf16(a[i], x[j], acc[i][j], 0, 0, 0);
#pragma unroll
    for (int i = 0; i < 4; ++i)
      x[i] = *(const short8*)(As[1] + (wm + i * 16 + l16) * 32 + aslot);
#pragma unroll
    for (int i = 0; i < 4; ++i)
#pragma unroll
      for (int j = 0; j < 4; ++j)
        acc[i][j] = __builtin_amdgcn_mfma_f32_16x16x32_bf16(x[i], b[j], acc[i][j], 0, 0, 0);
    __syncthreads();
  }

#pragma unroll
  for (int i = 0; i < 4; ++i)
#pragma unroll
    for (int j = 0; j < 4; ++j)
#pragma unroll
      for (int r = 0; r < 4; ++r) {
        int row = m0 + wm + i * 16 + quad * 4 + r;
        int col = n0 + wn + j * 16 + l16;
        C[(size_t)row * SEQ + col] = acc[i][j][r] * scale;
      }
}

// PV: Obuf[z] = P[dense, lda=4096] * VT^T over k-range z. R12: split-K=2
// (1024 blocks: 32m x 16n x 2z, XCD-swizzled flat grid), 128m x 64n tile,
// 24 KB LDS, BK=64, 32x32x16 MFMA (layouts HW-verified R8), plain stores.
__global__ __launch_bounds__(256)
void gemm_pv(const ushort_t* __restrict__ P, const ushort_t* __restrict__ Vt,
             float* __restrict__ Obuf) {
  const int id = blockIdx.x;
  const int g = ((id >> 7) << 3) | (id & 7);   // (m,z) group, 0..63
  const int jn = (id >> 3) & 15;               // n tile (64-wide)
  const int z = g & 1, m = g >> 1;
  const int m0 = m * 128, n0 = jn * 64, kbeg = z * 2048;
  float* Ob = Obuf + (size_t)z * SEQ * DM;

  __shared__ ushort_t As[128 * 64];   // 16 KB
  __shared__ ushort_t Bs[64 * 64];    //  8 KB
  const int t = threadIdx.x;
  const int wave = t >> 6, lane = t & 63;
  const int l32 = lane & 31, khalf = lane >> 5;
  const int wm = (wave & 1) * 64, wn = (wave >> 1) * 32;
  const int srow = lane >> 3;
  const int gcol = (((lane & 7) - srow) & 7) * 8;
  const int rrot = lane & 7;   // (operand row)&7 == l32&7 == lane&7

  f32x16 acc[2] = {};
  for (int k0 = kbeg; k0 < kbeg + 2048; k0 += 64) {
#pragma unroll
    for (int i = 0; i < 4; ++i) {
      int c = wave * 4 + i;  // 8-row chunk, 0..15 (A: 128 rows)
      async_copy16(P + (size_t)(m0 + c * 8 + srow) * 4096 + k0 + gcol,
                   As + c * 512);
    }
#pragma unroll
    for (int i = 0; i < 2; ++i) {
      int c = wave * 2 + i;  // 8-row chunk, 0..7 (B: 64 rows)
      async_copy16(Vt + (size_t)(n0 + c * 8 + srow) * SEQ + k0 + gcol,
                   Bs + c * 512);
    }
    __syncthreads();
#pragma unroll
    for (int q = 0; q < 4; ++q) {            // k-step of 16 within the chunk
      const int slot = ((q * 2 + khalf + rrot) & 7) * 8;
      short8 b = *(const short8*)(Bs + (wn + l32) * 64 + slot);
#pragma unroll
      for (int i = 0; i < 2; ++i) {
        short8 a = *(const short8*)(As + (wm + i * 32 + l32) * 64 + slot);
        acc[i] = __builtin_amdgcn_mfma_f32_32x32x16_bf16(a, b, acc[i], 0, 0, 0);
      }
    }
    __syncthreads();
  }
#pragma unroll
  for (int i = 0; i < 2; ++i)
#pragma unroll
    for (int r = 0; r < 16; ++r) {
      int row = m0 + wm + i * 32 + (r & 3) + 8 * (r >> 2) + 4 * khalf;
      int col = n0 + wn + l32;
      Ob[(size_t)row * DM + col] = acc[i][r];
    }
}

// out = Obuf[0] + Obuf[1], float4-vectorized.
__global__ __launch_bounds__(256)
void reduce2(const float* __restrict__ B, float* __restrict__ out) {
  const size_t i = ((size_t)blockIdx.x * 256 + threadIdx.x) * 4;
  const size_t n = (size_t)SEQ * DM;
  float4 s0 = *(const float4*)(B + i);
  float4 s1 = *(const float4*)(B + n + i);
  float4 o;
  o.x = s0.x + s1.x; o.y = s0.y + s1.y;
  o.z = s0.z + s1.z; o.w = s0.w + s1.w;
  *(float4*)(out + i) = o;
}

// Merged prep: z<3 -> W transpose+split into Wall; z==3 -> x split into Xp.
// Grid (16, 64, 4); W-paths no-op for by>=16.
__global__ __launch_bounds__(256)
void prep(const float* __restrict__ x, const float* __restrict__ W0,
          const float* __restrict__ W1, const float* __restrict__ W2,
          ushort_t* __restrict__ Xp, ushort_t* __restrict__ Wall) {
  const int zz = blockIdx.z;
  const int tx = threadIdx.x & 63, ty = threadIdx.x >> 6;
  if (zz == 3) {
    const int bc = blockIdx.x * 64, br = blockIdx.y * 64;
#pragma unroll
    for (int i = ty; i < 64; i += 4) {
      float v = x[(size_t)(br + i) * 1024 + bc + tx];
      ushort_t h = f2bf(v);
      Xp[(size_t)(br + i) * 2048 + bc + tx] = h;
      Xp[(size_t)(br + i) * 2048 + 1024 + bc + tx] = f2bf(v - bf2f(h));
    }
    return;
  }
  if (blockIdx.y >= 16) return;
  const float* W = (zz == 0) ? W0 : (zz == 1) ? W1 : W2;
  ushort_t* Wo = Wall + (size_t)zz * DM * 2048;
  __shared__ float tile[64][65];
  const int bn = blockIdx.x * 64, bk = blockIdx.y * 64;
#pragma unroll
  for (int i = ty; i < 64; i += 4)
    tile[i][tx] = W[(size_t)(bk + i) * DM + bn + tx];
  __syncthreads();
#pragma unroll
  for (int i = ty; i < 64; i += 4) {
    float v = tile[tx][i];
    ushort_t h = f2bf(v);
    Wo[(size_t)(bn + i) * 2048 + bk + tx] = h;
    Wo[(size_t)(bn + i) * 2048 + 1024 + bk + tx] = f2bf(v - bf2f(h));
  }
}

// one block per row; reads fp32 scores row (stride SEQ), writes dense bf16 P row
__global__ __launch_bounds__(256)
void softmax_rows(const float* __restrict__ S, ushort_t* __restrict__ Pd) {
  const int row = blockIdx.x;
  const int t = threadIdx.x, lane = t & 63, wave = t >> 6;
  const float4* s4 = (const float4*)(S + (size_t)row * SEQ);
  float4 v[4];
  float m = -3.4e38f;
#pragma unroll
  for (int i = 0; i < 4; ++i) {
    v[i] = s4[i * 256 + t];
    m = fmaxf(m, fmaxf(fmaxf(v[i].x, v[i].y), fmaxf(v[i].z, v[i].w)));
  }
  __shared__ float redm[4], reds[4];
#pragma unroll
  for (int o = 32; o; o >>= 1) m = fmaxf(m, __shfl_xor(m, o));
  if (lane == 0) redm[wave] = m;
  __syncthreads();
  m = fmaxf(fmaxf(redm[0], redm[1]), fmaxf(redm[2], redm[3]));
  float sum = 0.f;
#pragma unroll
  for (int i = 0; i < 4; ++i) {
    v[i].x = __expf(v[i].x - m); v[i].y = __expf(v[i].y - m);
    v[i].z = __expf(v[i].z - m); v[i].w = __expf(v[i].w - m);
    sum += v[i].x + v[i].y + v[i].z + v[i].w;
  }
#pragma unroll
  for (int o = 32; o; o >>= 1) sum += __shfl_xor(sum, o);
  if (lane == 0) reds[wave] = sum;
  __syncthreads();
  const float inv = 1.f / (reds[0] + reds[1] + reds[2] + reds[3]);
  ushort4* p4 = (ushort4*)(Pd + (size_t)row * SEQ);
#pragma unroll
  for (int i = 0; i < 4; ++i) {
    ushort4 o;
    o.x = f2bf(v[i].x * inv); o.y = f2bf(v[i].y * inv);
    o.z = f2bf(v[i].z * inv); o.w = f2bf(v[i].w * inv);
    p4[i * 256 + t] = o;
  }
}

extern "C" void kernel_launch(void* const* d_in, const int* in_sizes, int n_in,
                              void* d_out, int out_size, void* d_ws, size_t ws_size,
                              hipStream_t stream) {
  const float* x  = (const float*)d_in[0];
  const float* Wq = (const float*)d_in[1];
  const float* Wk = (const float*)d_in[2];
  const float* Wv = (const float*)d_in[3];
  float* out = (float*)d_out;
  char* ws = (char*)d_ws;
  const size_t MB = (size_t)1 << 20;
  // ws layout (140 MB). Pd aliases Xp/Wall/Qb-head (all dead at softmax);
  // Obuf aliases S (dead after softmax).
  ushort_t* Xp   = (ushort_t*)(ws + 0 * MB);    // 16 MB [SEQ x 2048] hi|lo
  ushort_t* Wall = (ushort_t*)(ws + 16 * MB);   // 12 MB [3072 x 2048]
  ushort_t* Qb   = (ushort_t*)(ws + 28 * MB);   // 16 MB [SEQ x 2048]
  ushort_t* Kb   = (ushort_t*)(ws + 44 * MB);   // 16 MB
  ushort_t* VT   = (ushort_t*)(ws + 68 * MB);   //  8 MB [DM x SEQ]
  float*    S    = (float*)(ws + 76 * MB);      // 64 MB [SEQ x SEQ]
  ushort_t* Pd   = (ushort_t*)(ws + 0 * MB);    // 32 MB [SEQ x SEQ] dense bf16
  float*    Obuf = (float*)(ws + 76 * MB);      // 32 MB = 2 x [SEQ x DM] fp32

  // 1) split inputs into bf16 hi/lo pairs (x elementwise, W transposed)
  prep<<<dim3(16, 64, 4), 256, 0, stream>>>(x, Wq, Wk, Wv, Xp, Wall);

  // 2) fused QKV projection (768 blocks = 3/CU); V path writes VT directly
  gemm_qkv<<<dim3(3 * DM / 128, SEQ / 128), 256, 0, stream>>>(
      Xp, Wall, Qb, Kb, VT);

  // 3) scores = Q K^T / 32, fp32
  gemm_sc<<<dim3(SEQ / 128, SEQ / 128), 256, 0, stream>>>(Qb, Kb, S, 0.03125f);

  // 4) row softmax -> dense bf16 P (over dead Xp/Wall region)
  softmax_rows<<<SEQ, 256, 0, stream>>>(S, Pd);

  // 5) partial PV into 2 split-K buffers (1024 blocks, 128x64 tiles)
  gemm_pv<<<1024, 256, 0, stream>>>(Pd, VT, Obuf);

  // 6) out = sum of the 2 partials
  reduce2<<<SEQ * DM / 1024, 256, 0, stream>>>(Obuf, out);
}